// Round 1
// baseline (426.920 us; speedup 1.0000x reference)
//
#include <hip/hip_runtime.h>
#include <stdint.h>

#define B_ 4
#define T_ 64
#define P_ 256
#define E_ 512
#define H_ 8
#define D_ 64
#define NF 1536
#define MCH 16384   // tokens per b-chunk (T_*P_)

typedef unsigned short u16;
typedef __attribute__((ext_vector_type(8))) __bf16 bf16x8;
typedef __attribute__((ext_vector_type(4))) float f32x4;

__device__ __forceinline__ u16 f2bf(float x) {
  union { float f; uint32_t u; } a; a.f = x;
  uint32_t u = a.u;
  uint32_t r = (u + 0x7FFFu + ((u >> 16) & 1u)) >> 16;
  return (u16)r;
}

__device__ __forceinline__ bf16x8 ld8(const u16* p) {
  union { uint4 u; bf16x8 b; } t;
  t.u = *reinterpret_cast<const uint4*>(p);
  return t.b;
}

typedef __attribute__((address_space(3))) void lds_void;
typedef __attribute__((address_space(1))) void g_void;
__device__ __forceinline__ void gl_lds16(const void* g, void* l) {
  __builtin_amdgcn_global_load_lds((g_void*)g, (lds_void*)l, 16, 0, 0);
}

__device__ __forceinline__ f32x4 mfma16(bf16x8 a, bf16x8 b, f32x4 c) {
  return __builtin_amdgcn_mfma_f32_16x16x32_bf16(a, b, c, 0, 0, 0);
}

// ---------------- K0: f32 -> bf16 convert (8 elems/thread) ----------------
__global__ void cvt_bf16(const float* __restrict__ src, u16* __restrict__ dst, int n8) {
  int i = blockIdx.x * blockDim.x + threadIdx.x;
  if (i >= n8) return;
  const float4* s = reinterpret_cast<const float4*>(src) + (size_t)i * 2;
  float4 a = s[0], b = s[1];
  union { u16 u[8]; uint4 v; } t;
  t.u[0] = f2bf(a.x); t.u[1] = f2bf(a.y); t.u[2] = f2bf(a.z); t.u[3] = f2bf(a.w);
  t.u[4] = f2bf(b.x); t.u[5] = f2bf(b.y); t.u[6] = f2bf(b.z); t.u[7] = f2bf(b.w);
  reinterpret_cast<uint4*>(dst)[i] = t.v;
}

// ---------------- K1: qkv = x_bf @ Wqkv^T + bias  (M=16384,N=1536,K=512) ----
// 128x128 tile, BK=64, 4 waves (2x2), global_load_lds width-16 staging.
__global__ __launch_bounds__(256) void k1_qkv(
    const u16* __restrict__ xbf,    // [MCH][512]
    const u16* __restrict__ wqkv,   // [1536][512]  (Wq;Wk;Wv rows, K-contig)
    const float* __restrict__ bq, const float* __restrict__ bk, const float* __restrict__ bv,
    u16* __restrict__ qkv)          // [MCH][1536]
{
  __shared__ u16 As[128 * 64];
  __shared__ u16 Bs[128 * 64];
  const int tid = threadIdx.x;
  const int lane = tid & 63;
  const int wid = tid >> 6;
  const int m0 = blockIdx.y * 128;
  const int n0 = blockIdx.x * 128;
  const int wm = (wid >> 1) * 64;
  const int wn = (wid & 1) * 64;
  const int g4 = lane >> 4;

  f32x4 acc[4][4];
#pragma unroll
  for (int i = 0; i < 4; i++)
#pragma unroll
    for (int j = 0; j < 4; j++) { f32x4 z = {0.f, 0.f, 0.f, 0.f}; acc[i][j] = z; }

  const u16* ga = xbf + (size_t)m0 * E_;
  const u16* gb = wqkv + (size_t)n0 * E_;
  const int lrow = lane >> 3;          // 0..7 within 8-row chunk
  const int lcol = (lane & 7) * 8;     // 0..56

  for (int kt = 0; kt < E_ / 64; ++kt) {
    const int k0 = kt * 64;
    __syncthreads();
#pragma unroll
    for (int p = 0; p < 4; ++p) {
      const int ch = wid * 4 + p;      // 0..15 ; chunk = 8 rows x 128B
      const int r = ch * 8 + lrow;
      gl_lds16(ga + (size_t)r * E_ + k0 + lcol, As + ch * 512);
      gl_lds16(gb + (size_t)r * E_ + k0 + lcol, Bs + ch * 512);
    }
    __syncthreads();
#pragma unroll
    for (int ks = 0; ks < 2; ++ks) {
      const int fc = ks * 32 + g4 * 8;
      bf16x8 af[4], bfr[4];
#pragma unroll
      for (int mi = 0; mi < 4; mi++) af[mi] = ld8(As + (wm + mi * 16 + (lane & 15)) * 64 + fc);
#pragma unroll
      for (int ni = 0; ni < 4; ni++) bfr[ni] = ld8(Bs + (wn + ni * 16 + (lane & 15)) * 64 + fc);
#pragma unroll
      for (int mi = 0; mi < 4; mi++)
#pragma unroll
        for (int ni = 0; ni < 4; ni++)
          acc[mi][ni] = mfma16(af[mi], bfr[ni], acc[mi][ni]);
    }
  }
  // epilogue: + bias, store bf16 token-major. 16 lanes = 16 consecutive f -> 32B sectors.
#pragma unroll
  for (int ni = 0; ni < 4; ni++) {
    const int fcol = n0 + wn + ni * 16 + (lane & 15);
    const float bias = fcol < 512 ? bq[fcol] : (fcol < 1024 ? bk[fcol - 512] : bv[fcol - 1024]);
#pragma unroll
    for (int mi = 0; mi < 4; mi++)
#pragma unroll
      for (int r = 0; r < 4; r++) {
        const int row = m0 + wm + mi * 16 + g4 * 4 + r;
        qkv[(size_t)row * NF + fcol] = f2bf(acc[mi][ni][r] + bias);
      }
  }
}

// ---------------- K2: per-(p,h) causal attention over T=64, D=64 ------------
// 1 wave per (p,h); 4 waves/block. Full S in registers, P^ via padded LDS.
__global__ __launch_bounds__(256) void k2_attn(
    const u16* __restrict__ qkv,   // [MCH][1536], token n = t*P_+p
    u16* __restrict__ o)           // [MCH][512]
{
  __shared__ u16 Pl[4][64 * 72];
  const int tid = threadIdx.x, lane = tid & 63, wid = tid >> 6;
  const int gw = blockIdx.x * 4 + wid;     // 0..2047
  const int h = gw & 7, p = gw >> 3;
  const int g4 = lane >> 4;
  const size_t ts = (size_t)P_ * NF;       // t-stride in elements
  const u16* qb = qkv + (size_t)p * NF + h * D_;
  const u16* kb = qb + 512;
  const u16* vb = qb + 1024;

  bf16x8 qf[4][2], kf[4][2];
#pragma unroll
  for (int i = 0; i < 4; i++)
#pragma unroll
    for (int ks = 0; ks < 2; ks++) {
      const int rr = i * 16 + (lane & 15);
      const int dc = ks * 32 + g4 * 8;
      qf[i][ks] = ld8(qb + (size_t)rr * ts + dc);
      kf[i][ks] = ld8(kb + (size_t)rr * ts + dc);
    }
  f32x4 S[4][4];
#pragma unroll
  for (int i = 0; i < 4; i++)
#pragma unroll
    for (int j = 0; j < 4; j++) { f32x4 z = {0.f, 0.f, 0.f, 0.f}; S[i][j] = z; }
#pragma unroll
  for (int ks = 0; ks < 2; ks++)
#pragma unroll
    for (int mi = 0; mi < 4; mi++)
#pragma unroll
      for (int ni = 0; ni < 4; ni++)
        S[mi][ni] = mfma16(qf[mi][ks], kf[ni][ks], S[mi][ni]);

  // softmax rows live on 16 lanes (same lane>>4), 4 cols each
  u16* pw = &Pl[wid][0];
#pragma unroll
  for (int mi = 0; mi < 4; mi++)
#pragma unroll
    for (int r = 0; r < 4; r++) {
      const int t = mi * 16 + g4 * 4 + r;
      float v[4]; float mx = -1e30f;
#pragma unroll
      for (int ni = 0; ni < 4; ni++) {
        const int s = ni * 16 + (lane & 15);
        v[ni] = (s <= t) ? S[mi][ni][r] * 0.125f : -1e30f;
        mx = fmaxf(mx, v[ni]);
      }
      mx = fmaxf(mx, __shfl_xor(mx, 1));
      mx = fmaxf(mx, __shfl_xor(mx, 2));
      mx = fmaxf(mx, __shfl_xor(mx, 4));
      mx = fmaxf(mx, __shfl_xor(mx, 8));
      float sum = 0.f; float pv[4];
#pragma unroll
      for (int ni = 0; ni < 4; ni++) {
        const int s = ni * 16 + (lane & 15);
        pv[ni] = (s <= t) ? __expf(v[ni] - mx) : 0.f;
        sum += pv[ni];
      }
      sum += __shfl_xor(sum, 1);
      sum += __shfl_xor(sum, 2);
      sum += __shfl_xor(sum, 4);
      sum += __shfl_xor(sum, 8);
      const float inv = 1.0f / sum;
#pragma unroll
      for (int ni = 0; ni < 4; ni++) {
        const int s = ni * 16 + (lane & 15);
        pw[t * 72 + s] = f2bf(pv[ni] * inv);
      }
    }
  __syncthreads();

  // O = P^ @ V
  f32x4 O[4][4];
#pragma unroll
  for (int i = 0; i < 4; i++)
#pragma unroll
    for (int j = 0; j < 4; j++) { f32x4 z = {0.f, 0.f, 0.f, 0.f}; O[i][j] = z; }
#pragma unroll
  for (int ks = 0; ks < 2; ks++) {
    bf16x8 pa[4], vf[4];
#pragma unroll
    for (int mi = 0; mi < 4; mi++)
      pa[mi] = ld8(pw + (mi * 16 + (lane & 15)) * 72 + ks * 32 + g4 * 8);
#pragma unroll
    for (int ni = 0; ni < 4; ni++) {
      union { u16 u[8]; bf16x8 b; } tv;
#pragma unroll
      for (int j = 0; j < 8; j++) {
        const int s = ks * 32 + g4 * 8 + j;
        tv.u[j] = vb[(size_t)s * ts + ni * 16 + (lane & 15)];
      }
      vf[ni] = tv.b;
    }
#pragma unroll
    for (int mi = 0; mi < 4; mi++)
#pragma unroll
      for (int ni = 0; ni < 4; ni++)
        O[mi][ni] = mfma16(pa[mi], vf[ni], O[mi][ni]);
  }
#pragma unroll
  for (int mi = 0; mi < 4; mi++)
#pragma unroll
    for (int ni = 0; ni < 4; ni++)
#pragma unroll
      for (int r = 0; r < 4; r++) {
        const int t = mi * 16 + g4 * 4 + r;
        const int d = ni * 16 + (lane & 15);
        o[((size_t)t * P_ + p) * E_ + h * D_ + d] = f2bf(O[mi][ni][r]);
      }
}

// ---------------- K3: out = LN(x + o @ Wo^T + bo) ---------------------------
// BM=32 rows x full N=512 per block (LN needs whole row). 4 waves, BK=32.
__global__ __launch_bounds__(256) void k3_out(
    const u16* __restrict__ obf,   // [MCH][512]
    const u16* __restrict__ wo,    // [512][512]
    const float* __restrict__ bo,
    const float* __restrict__ x,   // [MCH][512] f32
    const float* __restrict__ lng, const float* __restrict__ lnb,
    float* __restrict__ out)       // [MCH][512] f32
{
  __shared__ u16 As[32 * 32];
  __shared__ u16 Bs[512 * 32];
  __shared__ float redS[32][4];
  __shared__ float redQ[32][4];
  const int tid = threadIdx.x, lane = tid & 63, wid = tid >> 6;
  const int m0 = blockIdx.x * 32;
  const int g4 = lane >> 4;
  const int lr = lane >> 2;        // 0..15
  const int lc = (lane & 3) * 8;   // 0..24

  f32x4 acc[2][8];
#pragma unroll
  for (int i = 0; i < 2; i++)
#pragma unroll
    for (int j = 0; j < 8; j++) { f32x4 z = {0.f, 0.f, 0.f, 0.f}; acc[i][j] = z; }

  const u16* ga = obf + (size_t)m0 * E_;

  for (int kt = 0; kt < 16; ++kt) {
    const int k0 = kt * 32;
    __syncthreads();
    if (wid < 2) {   // A tile: 2 chunks of 16 rows x 64B
      gl_lds16(ga + (size_t)(wid * 16 + lr) * E_ + k0 + lc, As + wid * 512);
    }
#pragma unroll
    for (int pass = 0; pass < 8; ++pass) {   // B tile: 32 chunks
      const int ch = wid * 8 + pass;
      gl_lds16(wo + (size_t)(ch * 16 + lr) * E_ + k0 + lc, Bs + ch * 512);
    }
    __syncthreads();
    const int fc = g4 * 8;
    bf16x8 af[2], bfr[8];
#pragma unroll
    for (int mi = 0; mi < 2; mi++) af[mi] = ld8(As + (mi * 16 + (lane & 15)) * 32 + fc);
#pragma unroll
    for (int ni = 0; ni < 8; ni++) bfr[ni] = ld8(Bs + (wid * 128 + ni * 16 + (lane & 15)) * 32 + fc);
#pragma unroll
    for (int mi = 0; mi < 2; mi++)
#pragma unroll
      for (int ni = 0; ni < 8; ni++)
        acc[mi][ni] = mfma16(af[mi], bfr[ni], acc[mi][ni]);
  }

  // epilogue: y = acc + bo + x ; LayerNorm over 512 cols
  float gg[8], bb[8], bof[8];
#pragma unroll
  for (int ni = 0; ni < 8; ni++) {
    const int f = wid * 128 + ni * 16 + (lane & 15);
    gg[ni] = lng[f]; bb[ni] = lnb[f]; bof[ni] = bo[f];
  }
#pragma unroll
  for (int mi = 0; mi < 2; mi++)
#pragma unroll
    for (int r = 0; r < 4; r++) {
      const int n = m0 + mi * 16 + g4 * 4 + r;
#pragma unroll
      for (int ni = 0; ni < 8; ni++) {
        const int f = wid * 128 + ni * 16 + (lane & 15);
        acc[mi][ni][r] += bof[ni] + x[(size_t)n * E_ + f];
      }
    }
#pragma unroll
  for (int mi = 0; mi < 2; mi++)
#pragma unroll
    for (int r = 0; r < 4; r++) {
      float s = 0.f, q = 0.f;
#pragma unroll
      for (int ni = 0; ni < 8; ni++) { const float y = acc[mi][ni][r]; s += y; q += y * y; }
      s += __shfl_xor(s, 1); q += __shfl_xor(q, 1);
      s += __shfl_xor(s, 2); q += __shfl_xor(q, 2);
      s += __shfl_xor(s, 4); q += __shfl_xor(q, 4);
      s += __shfl_xor(s, 8); q += __shfl_xor(q, 8);
      if ((lane & 15) == 0) {
        const int rl = mi * 16 + g4 * 4 + r;
        redS[rl][wid] = s; redQ[rl][wid] = q;
      }
    }
  __syncthreads();
#pragma unroll
  for (int mi = 0; mi < 2; mi++)
#pragma unroll
    for (int r = 0; r < 4; r++) {
      const int rl = mi * 16 + g4 * 4 + r;
      const float Sx = redS[rl][0] + redS[rl][1] + redS[rl][2] + redS[rl][3];
      const float Qx = redQ[rl][0] + redQ[rl][1] + redQ[rl][2] + redQ[rl][3];
      const float mean = Sx * (1.0f / 512.0f);
      const float var = Qx * (1.0f / 512.0f) - mean * mean;
      const float rs = rsqrtf(var + 1e-5f);
      const int n = m0 + rl;
#pragma unroll
      for (int ni = 0; ni < 8; ni++) {
        const int f = wid * 128 + ni * 16 + (lane & 15);
        out[(size_t)n * E_ + f] = (acc[mi][ni][r] - mean) * rs * gg[ni] + bb[ni];
      }
    }
}

extern "C" void kernel_launch(void* const* d_in, const int* in_sizes, int n_in,
                              void* d_out, int out_size, void* d_ws, size_t ws_size,
                              hipStream_t stream) {
  const float* x   = (const float*)d_in[0];
  const float* Wq  = (const float*)d_in[1];
  const float* bq  = (const float*)d_in[2];
  const float* Wk  = (const float*)d_in[3];
  const float* bk  = (const float*)d_in[4];
  const float* Wv  = (const float*)d_in[5];
  const float* bv  = (const float*)d_in[6];
  const float* Wo  = (const float*)d_in[7];
  const float* bo  = (const float*)d_in[8];
  const float* lng = (const float*)d_in[9];
  const float* lnb = (const float*)d_in[10];
  float* out = (float*)d_out;

  uint8_t* ws = (uint8_t*)d_ws;
  u16* xbf  = (u16*)(ws);                   // 16,777,216 B
  u16* qkvc = (u16*)(ws + 16777216);        // 50,331,648 B
  u16* obf  = (u16*)(ws + 67108864);        // 16,777,216 B
  u16* wqkv = (u16*)(ws + 83886080);        //  1,572,864 B
  u16* wobf = (u16*)(ws + 85458944);        //    524,288 B (end: 85,983,232)

  cvt_bf16<<<128, 256, 0, stream>>>(Wq, wqkv,               E_ * E_ / 8);
  cvt_bf16<<<128, 256, 0, stream>>>(Wk, wqkv + E_ * E_,     E_ * E_ / 8);
  cvt_bf16<<<128, 256, 0, stream>>>(Wv, wqkv + 2 * E_ * E_, E_ * E_ / 8);
  cvt_bf16<<<128, 256, 0, stream>>>(Wo, wobf,               E_ * E_ / 8);

  for (int b = 0; b < B_; ++b) {
    const float* xb = x + (size_t)b * MCH * E_;
    cvt_bf16<<<4096, 256, 0, stream>>>(xb, xbf, MCH * E_ / 8);
    k1_qkv<<<dim3(12, 128), 256, 0, stream>>>(xbf, wqkv, bq, bk, bv, qkvc);
    k2_attn<<<512, 256, 0, stream>>>(qkvc, obf);
    k3_out<<<512, 256, 0, stream>>>(obf, wobf, bo, xb, lng, lnb, out + (size_t)b * MCH * E_);
  }
}